// Round 9
// baseline (111.625 us; speedup 1.0000x reference)
//
#include <hip/hip_runtime.h>
#include <stdint.h>

// Problem constants (LSHSoftmax): B=1024, D=512, N=500000, S=32768
#define B_DIM 1024
#define D_DIM 512
#define S_DIM 32768

typedef __attribute__((ext_vector_type(8))) short bf16x8;   // 8 bf16 = 4 VGPRs
typedef __attribute__((ext_vector_type(4))) float f32x4;
typedef __attribute__((ext_vector_type(8))) unsigned short u16x8;

__device__ __forceinline__ unsigned short f2bf(float f) {
  union { float f; uint32_t u; } x; x.f = f;
  uint32_t r = x.u + 0x7fffu + ((x.u >> 16) & 1u);   // RNE
  return (unsigned short)(r >> 16);
}

// v_cvt_pk_bf16_f32: D.lo16 = bf16(a), D.hi16 = bf16(b) — 1 inst per 2 elts.
__device__ __forceinline__ uint32_t cvtpk(float a, float b) {
  uint32_t r;
  asm("v_cvt_pk_bf16_f32 %0, %1, %2" : "=v"(r) : "v"(a), "v"(b));
  return r;
}

// Convert inputs A f32 -> bf16 once (2 MiB -> 1 MiB; shared by all 512 blocks,
// L2-resident everywhere).
__global__ __launch_bounds__(256) void conv_a(const float* __restrict__ A,
                                              unsigned short* __restrict__ Ab) {
  int gid = blockIdx.x * 256 + threadIdx.x;
  const float* src = A + (size_t)gid * 8;
  float4 v0 = *(const float4*)src;
  float4 v1 = *(const float4*)(src + 4);
  u16x8 o;
  o[0] = f2bf(v0.x); o[1] = f2bf(v0.y); o[2] = f2bf(v0.z); o[3] = f2bf(v0.w);
  o[4] = f2bf(v1.x); o[5] = f2bf(v1.y); o[6] = f2bf(v1.z); o[7] = f2bf(v1.w);
  *(u16x8*)(Ab + (size_t)gid * 8) = o;
}

// ---------------------------------------------------------------------------
// Column-resident fused gather+GEMM. Block b owns output cols n0=b*64..+64 and
// ALL 1024 rows:
//   phase 1 (once): gather W[ids[n0..n0+63]][:] (f32, 128 KB, read ONCE from
//     HBM) -> cvt_pk bf16 -> XOR-swizzled 64 KB LDS panel + bias into LDS.
//   phase 2 (barrier-free): 8 waves, each computes rows w*128..+128 in two
//     64-row M-tiles: A-frags straight from L2-hot Ab (16B/lane, 4 lanes/line),
//     B-frags from LDS (conflict-free swizzled ds_read_b128), 16 MFMA/chunk.
// No Wg round-trip (saves 68 MB HBM + 18 us serial prep), no barriers in the
// main loop, waves free-run so latency is hidden by 4 waves/SIMD TLP.
// LDS swizzle: 16B-slot s of row r stored at slot s^(r&7) (involution). Reads:
// 16 lanes span rows base..base+15 at one logical slot -> 8 bank-groups x2 =
// conflict-free. Gather writes: lane(r3,s3) writes phys slot j*8+s3 (linear)
// reading logical slot j*8+(s3^r3) from global (coalesced within 256B).
// ---------------------------------------------------------------------------
#define BN 64
#define NKK 16                    // K chunks of 32

__global__ __launch_bounds__(512, 4) void gemm_gather(const unsigned short* __restrict__ Ab,
                                                      const float* __restrict__ W,
                                                      const float* __restrict__ bias,
                                                      const int* __restrict__ ids,
                                                      float* __restrict__ out) {
  __shared__ __attribute__((aligned(16))) char ldsB[BN * 1024];   // 64 KiB
  __shared__ float biasLds[BN];

  const int tid = threadIdx.x;
  const int n0 = blockIdx.x * BN;

  // ---- Phase 1: gather + convert B panel (once) ----
  {
    const int row = tid >> 3;          // 0..63  (block-local col)
    const int s3 = tid & 7;
    const int r3 = row & 7;
    const int myid = ids[n0 + row];
    const float* srcW = W + (size_t)myid * D_DIM;
    char* dst = ldsB + row * 1024;
#pragma unroll
    for (int j = 0; j < 8; ++j) {
      // logical 16B-slot sl = j*8 + (s3^r3); phys slot = sl^(r&7) = j*8+s3.
      const float* p = srcW + j * 64 + (s3 ^ r3) * 8;
      float4 v0 = *(const float4*)p;
      float4 v1 = *(const float4*)(p + 4);
      int4 o;
      o.x = cvtpk(v0.x, v0.y); o.y = cvtpk(v0.z, v0.w);
      o.z = cvtpk(v1.x, v1.y); o.w = cvtpk(v1.z, v1.w);
      *(int4*)(dst + ((j * 8 + s3) << 4)) = o;
    }
    if (s3 == 0) biasLds[row] = bias[myid];
  }
  __syncthreads();                      // the only barrier

  // ---- Phase 2: barrier-free per-wave GEMM ----
  const int lane = tid & 63;
  const int w = tid >> 6;               // wave 0..7: rows w*128..+128
  const int lq = lane >> 4;             // 0..3
  const int l16 = lane & 15;
  const int h = l16 & 7;

  for (int mt = 0; mt < 2; ++mt) {      // two 64-row M-tiles per wave
    const int rowm = w * 128 + mt * 64;
    f32x4 acc[4][4];
#pragma unroll
    for (int m = 0; m < 4; ++m)
#pragma unroll
      for (int n = 0; n < 4; ++n)
        acc[m][n] = (f32x4)0.0f;

    const char* pa = (const char*)Ab + (size_t)(rowm + l16) * (D_DIM * 2) + lq * 16;

#pragma unroll
    for (int kk = 0; kk < NKK; ++kk) {
      const int slot = ((kk * 4 + lq) ^ h) << 4;   // swizzled 16B slot
      bf16x8 bv[4];
#pragma unroll
      for (int n = 0; n < 4; ++n)
        bv[n] = *(const bf16x8*)(ldsB + (n * 16 + l16) * 1024 + slot);

      __builtin_amdgcn_s_setprio(1);
#pragma unroll
      for (int m = 0; m < 4; ++m) {
        const bf16x8 af = *(const bf16x8*)(pa + m * 16 * 1024 + kk * 64);
#pragma unroll
        for (int n = 0; n < 4; ++n)
          acc[m][n] = __builtin_amdgcn_mfma_f32_16x16x32_bf16(af, bv[n],
                                                              acc[m][n], 0, 0, 0);
      }
      __builtin_amdgcn_s_setprio(0);
    }

    // Epilogue per M-tile (writes spread at ~50%/100% of each wave's work).
    // C layout: col = l16, row = lq*4 + r (m89-verified).
    const int lrow = lq * 4;
#pragma unroll
    for (int n = 0; n < 4; ++n) {
      const int col = n0 + n * 16 + l16;
      const float bvv = biasLds[n * 16 + l16];
#pragma unroll
      for (int m = 0; m < 4; ++m) {
        const int rbase = rowm + m * 16 + lrow;
#pragma unroll
        for (int r = 0; r < 4; ++r) {
          out[(size_t)(rbase + r) * S_DIM + col] = acc[m][n][r] + bvv;
        }
      }
    }
  }
}

extern "C" void kernel_launch(void* const* d_in, const int* in_sizes, int n_in,
                              void* d_out, int out_size, void* d_ws, size_t ws_size,
                              hipStream_t stream) {
  const float* inp  = (const float*)d_in[0];   // [B, D] f32
  const float* W    = (const float*)d_in[1];   // [N, D] f32
  const float* bias = (const float*)d_in[2];   // [N] f32
  const int*   ids  = (const int*)d_in[3];     // [S] int32
  float* out = (float*)d_out;                  // [B, S] f32

  unsigned short* Ab = (unsigned short*)d_ws;  // [B, D] bf16 (1 MiB)

  conv_a<<<(B_DIM * D_DIM / 8) / 256, 256, 0, stream>>>(inp, Ab);

  dim3 grid(S_DIM / BN);                       // 512 blocks, 2 per CU
  gemm_gather<<<grid, 512, 0, stream>>>(Ab, W, bias, ids, out);
}

// Round 10
// 104.203 us; speedup vs baseline: 1.0712x; 1.0712x over previous
//
#include <hip/hip_runtime.h>
#include <stdint.h>

// Problem constants (LSHSoftmax): B=1024, D=512, N=500000, S=32768
#define B_DIM 1024
#define D_DIM 512
#define S_DIM 32768

typedef __attribute__((ext_vector_type(8))) short bf16x8;   // 8 bf16 = 4 VGPRs
typedef __attribute__((ext_vector_type(4))) float f32x4;
typedef __attribute__((ext_vector_type(8))) unsigned short u16x8;

#define AS1 __attribute__((address_space(1)))
#define AS3 __attribute__((address_space(3)))

__device__ __forceinline__ unsigned short f2bf(float f) {
  union { float f; uint32_t u; } x; x.f = f;
  uint32_t r = x.u + 0x7fffu + ((x.u >> 16) & 1u);   // RNE
  return (unsigned short)(r >> 16);
}
__device__ __forceinline__ uint32_t cvtpk(float a, float b) {
  uint32_t r;
  asm("v_cvt_pk_bf16_f32 %0, %1, %2" : "=v"(r) : "v"(a), "v"(b));
  return r;
}

// Convert inputs A f32 -> bf16 once (1 MiB; L2-resident for all GEMM blocks).
__global__ __launch_bounds__(256) void conv_a(const float* __restrict__ A,
                                              unsigned short* __restrict__ Ab) {
  int gid = blockIdx.x * 256 + threadIdx.x;
  const float* src = A + (size_t)gid * 8;
  float4 v0 = *(const float4*)src;
  float4 v1 = *(const float4*)(src + 4);
  u16x8 o;
  o[0] = f2bf(v0.x); o[1] = f2bf(v0.y); o[2] = f2bf(v0.z); o[3] = f2bf(v0.w);
  o[4] = f2bf(v1.x); o[5] = f2bf(v1.y); o[6] = f2bf(v1.z); o[7] = f2bf(v1.w);
  *(u16x8*)(Ab + (size_t)gid * 8) = o;
}

// ---------------------------------------------------------------------------
// Column-block fused gather+GEMM, wave-private A pipeline (no loop barriers).
// Block b: cols n0=b*32, rows 0..1023.
//  Phase 1 (once): gather W[ids[n0..n0+31]][:] f32 (read ONCE from HBM) ->
//    cvt_pk bf16 -> swizzled 32 KB LDS panel. One __syncthreads().
//  Phase 2: 8 waves, each owns 128 rows; wave-private 2x8KB A double-buffer
//    filled by global_load_lds from L2-hot Ab, self-paced by counted
//    vmcnt(8) (8 loads/tile, depth 2). 16 K-iters of BK=32: 10 ds_read_b128
//    (2-way, free) + 16 MFMA. No s_barrier in the loop; 8 waves free-run so
//    stores/stages/MFMA interleave across waves.
// LDS swizzle (both A and B, 64B rows paired into 128B lines):
//    slot(row,q) = (((row&1)<<2)|q) ^ ((row>>1)&7)   [^ (chunk&7) for B]
// A write side: linear gload_lds dest, inverse-permuted global source.
// B write side: reg-staged (cvt) so swizzled ds_write directly.
// LDS: A 8w x 2 x 8KB = 128 KB @0, B 32 KB @131072 -> 160 KB, 1 block/CU,
// 1024 blocks = 4 generations (later gathers overlap earlier compute).
// ---------------------------------------------------------------------------
#define BN 32
#define NKT 16                      // K chunks of 32
#define B_OFF 131072

__global__ __launch_bounds__(512, 2) void gemm_gather(const unsigned short* __restrict__ Ab,
                                                      const float* __restrict__ W,
                                                      const float* __restrict__ bias,
                                                      const int* __restrict__ ids,
                                                      float* __restrict__ out) {
  __shared__ __attribute__((aligned(16))) char lds[163840];   // 160 KiB exactly

  const int tid = threadIdx.x;
  const int n0 = blockIdx.x * BN;

  // ---- Phase 1: gather + convert B panel (once) ----
  {
    const int col = tid >> 4;        // 0..31 (block-local output col)
    const int c = tid & 15;          // k-chunk 0..15 (32 f32 each)
    const int myid = ids[n0 + col];
    const float* srcW = W + (size_t)myid * D_DIM + c * 32;
    char* breg = lds + B_OFF + c * 2048 + (col >> 1) * 128;
    const int sx = (col >> 1) & 7;
#pragma unroll
    for (int q = 0; q < 4; ++q) {
      float4 a = *(const float4*)(srcW + q * 8);
      float4 b = *(const float4*)(srcW + q * 8 + 4);
      int4 o;
      o.x = cvtpk(a.x, a.y); o.y = cvtpk(a.z, a.w);
      o.z = cvtpk(b.x, b.y); o.w = cvtpk(b.z, b.w);
      const int slot = ((((col & 1) << 2) | q) ^ sx) ^ (c & 7);
      *(int4*)(breg + slot * 16) = o;
    }
  }

  const int lane = tid & 63;
  const int wv = tid >> 6;           // wave 0..7: rows wv*128..+128
  const int lq = lane >> 4;          // 0..3
  const int l16 = lane & 15;
  const int wm = wv * 128;

  // bias for epilogue (2 cols/lane), read while phase-1 writes drain.
  const float bb0 = bias[ids[n0 + l16]];
  const float bb1 = bias[ids[n0 + 16 + l16]];

  __syncthreads();                   // the only block-wide barrier

  // ---- Phase 2: wave-private pipelined GEMM ----
  char* aw = lds + wv * 16384;       // this wave's two 8 KB A buffers

  // Stage-source pointers: phys 16B-slot p = i*64+lane of the 8KB tile;
  // inverse of slot swizzle: s0 = (p&7)^((p>>3)&7), row = (p>>3)*2+(s0>>2),
  // q = s0&3.
  const char* abase[8];
#pragma unroll
  for (int i = 0; i < 8; ++i) {
    const int p = i * 64 + lane;
    const int ln = p >> 3;
    const int s0 = (p & 7) ^ (ln & 7);
    const int row = ln * 2 + (s0 >> 2);
    abase[i] = (const char*)Ab + (size_t)(wm + row) * (D_DIM * 2) + (s0 & 3) * 16;
  }
  auto stageA = [&](int kt) {
    char* dst = aw + (kt & 1) * 8192;
#pragma unroll
    for (int i = 0; i < 8; ++i)
      __builtin_amdgcn_global_load_lds((const AS1 void*)(abase[i] + kt * 64),
                                       (AS3 void*)(dst + i * 1024), 16, 0, 0);
  };

  // A-fragment offsets within an 8KB tile (row = m*16+l16, k-quarter lq).
  int aoff[8];
#pragma unroll
  for (int m = 0; m < 8; ++m) {
    const int row = m * 16 + l16;
    const int slot = (((row & 1) << 2) | lq) ^ ((row >> 1) & 7);
    aoff[m] = (row >> 1) * 128 + slot * 16;
  }
  // B-fragment bases (chunk-XOR applied per kk).
  int bln[2], bsl[2];
#pragma unroll
  for (int n = 0; n < 2; ++n) {
    const int col = n * 16 + l16;
    bln[n] = B_OFF + (col >> 1) * 128;
    bsl[n] = (((col & 1) << 2) | lq) ^ ((col >> 1) & 7);
  }

  f32x4 acc[8][2];
#pragma unroll
  for (int m = 0; m < 8; ++m)
#pragma unroll
    for (int n = 0; n < 2; ++n)
      acc[m][n] = (f32x4)0.0f;

  stageA(0);
  stageA(1);

#pragma unroll 2
  for (int kt = 0; kt < NKT; ++kt) {
    if (kt < NKT - 1)
      asm volatile("s_waitcnt vmcnt(8)" ::: "memory");   // tile kt landed
    else
      asm volatile("s_waitcnt vmcnt(0)" ::: "memory");

    const char* tb = aw + (kt & 1) * 8192;
    bf16x8 af[8], bv[2];
#pragma unroll
    for (int m = 0; m < 8; ++m) af[m] = *(const bf16x8*)(tb + aoff[m]);
    {
      const int cx = (kt & 7) << 4;
#pragma unroll
      for (int n = 0; n < 2; ++n)
        bv[n] = *(const bf16x8*)(lds + bln[n] + kt * 2048 + ((bsl[n] << 4) ^ cx));
    }

    __builtin_amdgcn_s_setprio(1);
#pragma unroll
    for (int m = 0; m < 8; ++m)
#pragma unroll
      for (int n = 0; n < 2; ++n)
        acc[m][n] = __builtin_amdgcn_mfma_f32_16x16x32_bf16(af[m], bv[n],
                                                            acc[m][n], 0, 0, 0);
    __builtin_amdgcn_s_setprio(0);

    // Refill the buffer just consumed (wave-private; af already in regs —
    // the compiler's lgkmcnt before the MFMAs ordered the reads).
    __builtin_amdgcn_sched_barrier(0);
    if (kt < NKT - 2) stageA(kt + 2);
    __builtin_amdgcn_sched_barrier(0);
  }

  // ---- Epilogue: C[row][col] = acc + bias (col=l16, row=lq*4+r) ----
  const int lrow = lq * 4;
#pragma unroll
  for (int n = 0; n < 2; ++n) {
    const int col = n0 + n * 16 + l16;
    const float bvv = (n == 0) ? bb0 : bb1;
#pragma unroll
    for (int m = 0; m < 8; ++m) {
      const int rbase = wm + m * 16 + lrow;
#pragma unroll
      for (int r = 0; r < 4; ++r) {
        out[(size_t)(rbase + r) * S_DIM + col] = acc[m][n][r] + bvv;
      }
    }
  }
}

extern "C" void kernel_launch(void* const* d_in, const int* in_sizes, int n_in,
                              void* d_out, int out_size, void* d_ws, size_t ws_size,
                              hipStream_t stream) {
  const float* inp  = (const float*)d_in[0];   // [B, D] f32
  const float* W    = (const float*)d_in[1];   // [N, D] f32
  const float* bias = (const float*)d_in[2];   // [N] f32
  const int*   ids  = (const int*)d_in[3];     // [S] int32
  float* out = (float*)d_out;                  // [B, S] f32

  unsigned short* Ab = (unsigned short*)d_ws;  // [B, D] bf16 (1 MiB)

  conv_a<<<(B_DIM * D_DIM / 8) / 256, 256, 0, stream>>>(inp, Ab);

  dim3 grid(S_DIM / BN);                       // 1024 blocks, 1/CU, 4 gens
  gemm_gather<<<grid, 512, 0, stream>>>(Ab, W, bias, ids, out);
}

// Round 11
// 66.087 us; speedup vs baseline: 1.6891x; 1.5768x over previous
//
#include <hip/hip_runtime.h>
#include <stdint.h>

// Problem constants (LSHSoftmax): B=1024, D=512, N=500000, S=32768
#define B_DIM 1024
#define D_DIM 512
#define S_DIM 32768

typedef __attribute__((ext_vector_type(8))) short bf16x8;   // 8 bf16 = 4 VGPRs
typedef __attribute__((ext_vector_type(4))) float f32x4;
typedef __attribute__((ext_vector_type(8))) unsigned short u16x8;

#define AS1 __attribute__((address_space(1)))
#define AS3 __attribute__((address_space(3)))

__device__ __forceinline__ unsigned short f2bf(float f) {
  union { float f; uint32_t u; } x; x.f = f;
  uint32_t r = x.u + 0x7fffu + ((x.u >> 16) & 1u);   // RNE
  return (unsigned short)(r >> 16);
}
__device__ __forceinline__ uint32_t cvtpk(float a, float b) {
  uint32_t r;
  asm("v_cvt_pk_bf16_f32 %0, %1, %2" : "=v"(r) : "v"(a), "v"(b));
  return r;
}

// Convert inputs A f32 -> bf16 once (1 MiB; L2-resident for all GEMM blocks).
__global__ __launch_bounds__(256) void conv_a(const float* __restrict__ A,
                                              unsigned short* __restrict__ Ab) {
  int gid = blockIdx.x * 256 + threadIdx.x;
  const float* src = A + (size_t)gid * 8;
  float4 v0 = *(const float4*)src;
  float4 v1 = *(const float4*)(src + 4);
  u16x8 o;
  o[0] = f2bf(v0.x); o[1] = f2bf(v0.y); o[2] = f2bf(v0.z); o[3] = f2bf(v0.w);
  o[4] = f2bf(v1.x); o[5] = f2bf(v1.y); o[6] = f2bf(v1.z); o[7] = f2bf(v1.w);
  *(u16x8*)(Ab + (size_t)gid * 8) = o;
}

// ---------------------------------------------------------------------------
// Persistent-panel fused gather+GEMM. 256 blocks (1/CU), block b owns cols
// n0=b*128 and ALL 1024 rows (8 bm-tiles of 128):
//  Phase 1 (once/block): gather W[ids[n0..n0+127]][:] f32 (read ONCE from
//    HBM - no Wg round-trip, no prep kernel) -> cvt_pk bf16 -> swizzled
//    128 KB LDS panel. One __syncthreads() (drains vmcnt+lgkmcnt).
//  Phase 2: uniform 64-iter loop (g = bm*8+kt): r5's proven A pipeline
//    (2x16KB double-buffer, global_load_lds, counted vmcnt(2), raw barriers,
//    setprio) with B read from the persistent panel (no B staging, no B sync).
//    Epilogue (write 64KB + bias) after every 8th iter for that bm.
// A-reuse economics fixed: B-panel 128 wide => A traffic = 8*128KB = 1MB/CU.
// LDS: A 2x16KB @0 + B 128KB @32768 = 160 KB exactly. No grid tail.
// B swizzle: [col][64 16B-slots], slot' = slot ^ (col&7) (involution):
//   frag reads (16 lanes = 16 cols, one slot) spread 8 bank-groups -> free.
// A swizzle: r5's byte ^= ((row&7)<<4) via pre-swizzled gload source.
// ---------------------------------------------------------------------------
#define BN 128
#define NG 64                        // 8 bm x 8 kt
#define B_OFF 32768

__global__ __launch_bounds__(512, 2) void gemm_fused(const unsigned short* __restrict__ Ab,
                                                     const float* __restrict__ W,
                                                     const float* __restrict__ bias,
                                                     const int* __restrict__ ids,
                                                     float* __restrict__ out) {
  __shared__ __attribute__((aligned(16))) char lds[163840];   // 160 KiB

  const int tid = threadIdx.x;
  const int lane = tid & 63;
  const int w = tid >> 6;            // wave 0..7
  const int wr = w >> 2;             // wave row 0..1 (64 rows)
  const int wc = w & 3;              // wave col 0..3 (32 cols)
  const int lq = lane >> 4;          // 0..3
  const int l16 = lane & 15;
  const int n0 = blockIdx.x * BN;

  // ---- Phase 1: gather + convert the persistent B panel (once) ----
  {
    const int row = tid >> 2;        // 0..127 (block-local col = W-row slot)
    const int c = tid & 3;           // 4 threads per row
    const int myid = ids[n0 + row];
    const float* srcW = W + (size_t)myid * D_DIM;
    char* drow = lds + B_OFF + row * 1024;
    const int r7 = row & 7;
#pragma unroll
    for (int j = 0; j < 16; ++j) {
      // 4 lanes cover f32 [j*32, j*32+32) = one 128B line (coalesced).
      const float* p = srcW + j * 32 + c * 8;
      float4 a = *(const float4*)p;
      float4 b = *(const float4*)(p + 4);
      int4 o;
      o.x = cvtpk(a.x, a.y); o.y = cvtpk(a.z, a.w);
      o.z = cvtpk(b.x, b.y); o.w = cvtpk(b.z, b.w);
      const int slot = (c + j * 4) ^ r7;          // slot sl holds k in [sl*8,sl*8+8)
      *(int4*)(drow + slot * 16) = o;
    }
  }
  // bias for the epilogue (2 values/lane), issued before the sync drain.
  float bb[2];
#pragma unroll
  for (int n = 0; n < 2; ++n)
    bb[n] = bias[ids[n0 + wc * 32 + n * 16 + l16]];

  __syncthreads();                   // drains vmcnt(0)+lgkmcnt(0): panel ready

  // ---- Phase 2: A double-buffer pipeline (r5 scheme) + persistent B ----
  // A stage source: physical byte P of 16KB tile holds logical L = P^swz(P).
  const char* sA[2];
#pragma unroll
  for (int j = 0; j < 2; ++j) {
    const int P = j * 8192 + w * 1024 + lane * 16;
    const int L = P ^ (((P >> 7) & 7) << 4);
    sA[j] = (const char*)Ab + (size_t)(L >> 7) * 1024 + (L & 127);
  }
  auto stage = [&](int g) {          // tile g: bm=g>>3, kt=g&7
    const int off = ((g >> 3) << 17) + ((g & 7) << 7);
    char* bufa = lds + (g & 1) * 16384;
#pragma unroll
    for (int j = 0; j < 2; ++j)
      __builtin_amdgcn_global_load_lds((const AS1 void*)(sA[j] + off),
                                       (AS3 void*)(bufa + j * 8192 + w * 1024),
                                       16, 0, 0);
  };

  // Fragment address pieces.
  const int swz = (l16 & 7) << 4;
  int arow[4];                       // A: logical row*128
#pragma unroll
  for (int m = 0; m < 4; ++m) arow[m] = (wr * 64 + m * 16 + l16) * 128;
  int bbase[2], bx7[2];              // B: col*1024 base, col&7 xor
#pragma unroll
  for (int n = 0; n < 2; ++n) {
    const int col = wc * 32 + n * 16 + l16;
    bbase[n] = B_OFF + col * 1024;
    bx7[n] = col & 7;
  }

  f32x4 acc[4][2];
#pragma unroll
  for (int m = 0; m < 4; ++m)
#pragma unroll
    for (int n = 0; n < 2; ++n)
      acc[m][n] = (f32x4)0.0f;

  stage(0);

  for (int g = 0; g < NG; ++g) {
    __builtin_amdgcn_sched_barrier(0);
    if (g < NG - 1) {
      stage(g + 1);                  // other buffer, released at barrier g-1
      __builtin_amdgcn_sched_barrier(0);
      asm volatile("s_waitcnt vmcnt(2)" ::: "memory");   // tile g landed
    } else {
      asm volatile("s_waitcnt vmcnt(0)" ::: "memory");
    }
    __builtin_amdgcn_s_barrier();    // raw barrier: no full drain
    __builtin_amdgcn_sched_barrier(0);

    const char* bufa = lds + (g & 1) * 16384;
    const int ks = (g & 7) << 3;     // B slot base for this kt

#pragma unroll
    for (int kk = 0; kk < 2; ++kk) {
      bf16x8 af[4], bv[2];
#pragma unroll
      for (int m = 0; m < 4; ++m)
        af[m] = *(const bf16x8*)(bufa + ((arow[m] + kk * 64 + lq * 16) ^ swz));
#pragma unroll
      for (int n = 0; n < 2; ++n)
        bv[n] = *(const bf16x8*)(lds + bbase[n] +
                                 (((ks + kk * 4 + lq) ^ bx7[n]) << 4));
      __builtin_amdgcn_s_setprio(1);
#pragma unroll
      for (int m = 0; m < 4; ++m)
#pragma unroll
        for (int n = 0; n < 2; ++n)
          acc[m][n] = __builtin_amdgcn_mfma_f32_16x16x32_bf16(af[m], bv[n],
                                                              acc[m][n], 0, 0, 0);
      __builtin_amdgcn_s_setprio(0);
    }

    __builtin_amdgcn_sched_barrier(0);
    __builtin_amdgcn_s_barrier();    // all waves done with buf g&1

    if ((g & 7) == 7) {
      // ---- Epilogue for bm = g>>3: C[row][col] = acc + bias, then reset ----
      const int rt = (g >> 3) * 128 + wr * 64 + lq * 4;
#pragma unroll
      for (int n = 0; n < 2; ++n) {
        const int col = n0 + wc * 32 + n * 16 + l16;
#pragma unroll
        for (int m = 0; m < 4; ++m) {
          const int rbase = rt + m * 16;
#pragma unroll
          for (int r = 0; r < 4; ++r)
            out[(size_t)(rbase + r) * S_DIM + col] = acc[m][n][r] + bb[n];
          acc[m][n] = (f32x4)0.0f;
        }
      }
    }
  }
}

extern "C" void kernel_launch(void* const* d_in, const int* in_sizes, int n_in,
                              void* d_out, int out_size, void* d_ws, size_t ws_size,
                              hipStream_t stream) {
  const float* inp  = (const float*)d_in[0];   // [B, D] f32
  const float* W    = (const float*)d_in[1];   // [N, D] f32
  const float* bias = (const float*)d_in[2];   // [N] f32
  const int*   ids  = (const int*)d_in[3];     // [S] int32
  float* out = (float*)d_out;                  // [B, S] f32

  unsigned short* Ab = (unsigned short*)d_ws;  // [B, D] bf16 (1 MiB)

  conv_a<<<(B_DIM * D_DIM / 8) / 256, 256, 0, stream>>>(inp, Ab);

  dim3 grid(S_DIM / BN);                       // 256 blocks = 1 per CU
  gemm_fused<<<grid, 512, 0, stream>>>(Ab, W, bias, ids, out);
}